// Round 1
// baseline (1207.051 us; speedup 1.0000x reference)
//
#include <hip/hip_runtime.h>
#include <hip/hip_bf16.h>

#define B_ 2
#define NTOK 4096
#define DMODEL 1024
#define HEADS_ 16
#define DH 64
#define SEG_ 512
#define NW 8
#define PMEM 16
#define ROWS 8192      // B_*NTOK
#define QKVC 3072

// ---------------- RMSNorm ----------------
__global__ __launch_bounds__(256) void rmsnorm_kernel(const float* __restrict__ seq,
                                                      const float* __restrict__ g,
                                                      float* __restrict__ x) {
    int row = blockIdx.x;
    const float4* in = (const float4*)(seq + (size_t)row * DMODEL);
    float4* out = (float4*)(x + (size_t)row * DMODEL);
    int tid = threadIdx.x;
    float4 v = in[tid];
    float ss = v.x*v.x + v.y*v.y + v.z*v.z + v.w*v.w;
    #pragma unroll
    for (int off = 32; off >= 1; off >>= 1) ss += __shfl_xor(ss, off, 64);
    __shared__ float red[4];
    if ((tid & 63) == 0) red[tid >> 6] = ss;
    __syncthreads();
    float tot = red[0] + red[1] + red[2] + red[3];
    float scale = rsqrtf(tot * (1.0f/(float)DMODEL) + 1.1920929e-7f);
    float4 gv = ((const float4*)g)[tid];
    float4 o;
    o.x = v.x*scale*gv.x; o.y = v.y*scale*gv.y;
    o.z = v.z*scale*gv.z; o.w = v.w*scale*gv.w;
    out[tid] = o;
}

// ---------------- f32 tiled GEMM: C[M,N] = A[M,K] @ B[K,N], all row-major ----
// 128x128 tile, BK=16, 256 threads, 8x8 per thread.
__global__ __launch_bounds__(256, 2) void gemm_f32(const float* __restrict__ A,
                                                   const float* __restrict__ Bm,
                                                   float* __restrict__ C,
                                                   int M, int N, int K) {
    __shared__ float As[16][132];   // [k][m], padded
    __shared__ float Bs[16][132];   // [k][n], padded
    const int bm = blockIdx.y * 128;
    const int bn = blockIdx.x * 128;
    const int tid = threadIdx.x;
    const int tr = (tid >> 4) << 3;   // 0..120 step 8
    const int tc = (tid & 15) << 3;
    float acc[8][8];
    #pragma unroll
    for (int i = 0; i < 8; ++i)
        #pragma unroll
        for (int j = 0; j < 8; ++j) acc[i][j] = 0.f;

    for (int k0 = 0; k0 < K; k0 += 16) {
        #pragma unroll
        for (int l = 0; l < 2; ++l) {
            int r = (tid >> 2) + l*64;
            int c = (tid & 3) << 2;
            float4 a = *(const float4*)&A[(size_t)(bm + r)*K + k0 + c];
            As[c+0][r] = a.x; As[c+1][r] = a.y; As[c+2][r] = a.z; As[c+3][r] = a.w;
        }
        #pragma unroll
        for (int l = 0; l < 2; ++l) {
            int kr = (tid >> 5) + l*8;
            int c = (tid & 31) << 2;
            *(float4*)&Bs[kr][c] = *(const float4*)&Bm[(size_t)(k0 + kr)*N + bn + c];
        }
        __syncthreads();
        #pragma unroll
        for (int k = 0; k < 16; ++k) {
            float a[8], b[8];
            #pragma unroll
            for (int i = 0; i < 8; ++i) a[i] = As[k][tr + i];
            #pragma unroll
            for (int j = 0; j < 8; ++j) b[j] = Bs[k][tc + j];
            #pragma unroll
            for (int i = 0; i < 8; ++i)
                #pragma unroll
                for (int j = 0; j < 8; ++j)
                    acc[i][j] += a[i]*b[j];
        }
        __syncthreads();
    }
    #pragma unroll
    for (int i = 0; i < 8; ++i) {
        #pragma unroll
        for (int j = 0; j < 8; j += 4) {
            *(float4*)&C[(size_t)(bm + tr + i)*N + bn + tc + j] =
                make_float4(acc[i][j], acc[i][j+1], acc[i][j+2], acc[i][j+3]);
        }
    }
}

// ---------------- RoPE (interleaved pairs) on q,k sections of qkv ----------
__global__ __launch_bounds__(256) void rope_kernel(float* __restrict__ qkv) {
    int idx = blockIdx.x*256 + threadIdx.x;        // ROWS * 2048 / 4 threads
    int row = idx >> 9;                            // 512 float4 per row (q+k = 2048 cols)
    int c4  = (idx & 511) << 2;                    // col in [0,2048), same as col in qkv
    int n   = row & (NTOK - 1);                    // global position
    int d   = c4 & (DH - 1);
    int p0  = d >> 1;                              // first pair index
    float e0 = (float)p0 * (1.f/32.f);
    float inv0 = powf(10000.f, -e0);
    float inv1 = powf(10000.f, -(e0 + 1.f/32.f));
    float a0 = (float)n * inv0;
    float a1 = (float)n * inv1;
    float s0, c0, s1, c1;
    sincosf(a0, &s0, &c0);
    sincosf(a1, &s1, &c1);
    float* ptr = qkv + (size_t)row*QKVC + c4;
    float4 v = *(float4*)ptr;
    float4 o;
    o.x = v.x*c0 - v.y*s0;
    o.y = v.y*c0 + v.x*s0;
    o.z = v.z*c1 - v.w*s1;
    o.w = v.w*c1 + v.z*s1;
    *(float4*)ptr = o;
}

// ---------------- windowed causal attention with persistent-memory keys -----
// grid: x = row-block (2), y = head (16), z = segment (16 = b*8+w). 256 thr.
__global__ __launch_bounds__(256) void attn_kernel(const float* __restrict__ qkv,
                                                   const float* __restrict__ pm,
                                                   float* __restrict__ ao) {
    const int rb = blockIdx.x;
    const int h  = blockIdx.y;
    const int s  = blockIdx.z;
    const int b_idx = s >> 3, w_idx = s & 7;
    const int tid = threadIdx.x;
    const int i = rb*256 + tid;                    // query row in segment
    const size_t base_row = (size_t)b_idx*NTOK + (size_t)w_idx*SEG_;

    __shared__ float kb[64][68];
    __shared__ float vb[64][68];

    float q[DH];
    {
        const float* qrow = qkv + (base_row + i)*QKVC + h*DH;
        #pragma unroll
        for (int d = 0; d < DH; d += 4) {
            float4 t = *(const float4*)(qrow + d);
            q[d]=t.x; q[d+1]=t.y; q[d+2]=t.z; q[d+3]=t.w;
        }
    }
    float m = -3.0e38f, l = 0.0f;
    float acc[DH];
    #pragma unroll
    for (int d = 0; d < DH; ++d) acc[d] = 0.f;

    // persistent-memory chunk: 16 keys, visible to all rows
    {
        int j = tid >> 4, c = (tid & 15) << 2;
        *(float4*)&kb[j][c] = *(const float4*)&pm[((size_t)(0*HEADS_ + h)*PMEM + j)*DH + c];
        *(float4*)&vb[j][c] = *(const float4*)&pm[((size_t)(1*HEADS_ + h)*PMEM + j)*DH + c];
    }
    __syncthreads();
    #pragma unroll 1
    for (int j = 0; j < PMEM; ++j) {
        float sc = 0.f;
        #pragma unroll
        for (int d = 0; d < DH; ++d) sc += q[d]*kb[j][d];
        sc *= 0.125f;
        if (sc > m) {
            float corr = __expf(m - sc);
            l *= corr;
            #pragma unroll
            for (int d = 0; d < DH; ++d) acc[d] *= corr;
            m = sc;
        }
        float p = __expf(sc - m);
        l += p;
        #pragma unroll
        for (int d = 0; d < DH; ++d) acc[d] += p*vb[j][d];
    }

    // segment key chunks of 64 (causal)
    for (int c0 = 0; c0 < (rb+1)*256; c0 += 64) {
        __syncthreads();
        #pragma unroll
        for (int lld = 0; lld < 4; ++lld) {
            int lin = lld*256 + tid;
            int j = lin >> 4, c = (lin & 15) << 2;
            size_t grow = (base_row + c0 + j)*QKVC + h*DH;
            *(float4*)&kb[j][c] = *(const float4*)&qkv[grow + 1024 + c];
            *(float4*)&vb[j][c] = *(const float4*)&qkv[grow + 2048 + c];
        }
        __syncthreads();
        int jmax = min(64, i - c0 + 1);
        #pragma unroll 1
        for (int j = 0; j < jmax; ++j) {
            float sc = 0.f;
            #pragma unroll
            for (int d = 0; d < DH; ++d) sc += q[d]*kb[j][d];
            sc *= 0.125f;
            if (sc > m) {
                float corr = __expf(m - sc);
                l *= corr;
                #pragma unroll
                for (int d = 0; d < DH; ++d) acc[d] *= corr;
                m = sc;
            }
            float p = __expf(sc - m);
            l += p;
            #pragma unroll
            for (int d = 0; d < DH; ++d) acc[d] += p*vb[j][d];
        }
    }

    float inv = 1.0f / l;
    float* orow = ao + (base_row + i)*DMODEL + h*DH;
    #pragma unroll
    for (int d = 0; d < DH; d += 4) {
        *(float4*)(orow + d) = make_float4(acc[d]*inv, acc[d+1]*inv, acc[d+2]*inv, acc[d+3]*inv);
    }
}

extern "C" void kernel_launch(void* const* d_in, const int* in_sizes, int n_in,
                              void* d_out, int out_size, void* d_ws, size_t ws_size,
                              hipStream_t stream) {
    const float* seq  = (const float*)d_in[0];
    const float* g    = (const float*)d_in[1];
    const float* wqkv = (const float*)d_in[2];
    const float* wout = (const float*)d_in[3];
    const float* pm   = (const float*)d_in[4];
    float* out = (float*)d_out;

    float* x   = (float*)d_ws;                       // 8192*1024 f32 = 32 MiB
    float* qkv = x + (size_t)ROWS*DMODEL;            // 8192*3072 f32 = 96 MiB
    float* ao  = x;                                  // alias: x dead after QKV GEMM

    rmsnorm_kernel<<<ROWS, 256, 0, stream>>>(seq, g, x);
    gemm_f32<<<dim3(QKVC/128, ROWS/128), 256, 0, stream>>>(x, wqkv, qkv, ROWS, QKVC, DMODEL);
    rope_kernel<<<(ROWS*2048/4)/256, 256, 0, stream>>>(qkv);
    attn_kernel<<<dim3(2, 16, 16), 256, 0, stream>>>(qkv, pm, ao);
    gemm_f32<<<dim3(DMODEL/128, ROWS/128), 256, 0, stream>>>(ao, wout, out, ROWS, DMODEL, DMODEL);
}

// Round 2
// 523.440 us; speedup vs baseline: 2.3060x; 2.3060x over previous
//
#include <hip/hip_runtime.h>
#include <hip/hip_bf16.h>

typedef __attribute__((ext_vector_type(8))) short short8v;
typedef __attribute__((ext_vector_type(4))) float f32x4;

#define B_ 2
#define NTOK 4096
#define DMODEL 1024
#define HEADS_ 16
#define DH 64
#define SEG_ 512
#define PMEM 16
#define ROWS 8192      // B_*NTOK
#define QKVC 3072

// ---------------- RMSNorm -> bf16 ----------------
__global__ __launch_bounds__(256) void rmsnorm_bf16(const float* __restrict__ seq,
                                                    const float* __restrict__ g,
                                                    __hip_bfloat16* __restrict__ x) {
    int row = blockIdx.x;
    const float4* in = (const float4*)(seq + (size_t)row * DMODEL);
    int tid = threadIdx.x;
    float4 v = in[tid];
    float ss = v.x*v.x + v.y*v.y + v.z*v.z + v.w*v.w;
    #pragma unroll
    for (int off = 32; off >= 1; off >>= 1) ss += __shfl_xor(ss, off, 64);
    __shared__ float red[4];
    if ((tid & 63) == 0) red[tid >> 6] = ss;
    __syncthreads();
    float tot = red[0] + red[1] + red[2] + red[3];
    float scale = rsqrtf(tot * (1.0f/(float)DMODEL) + 1.1920929e-7f);
    float4 gv = ((const float4*)g)[tid];
    union { ushort4 u; __hip_bfloat16 h[4]; } pk;
    pk.h[0] = __float2bfloat16(v.x*scale*gv.x);
    pk.h[1] = __float2bfloat16(v.y*scale*gv.y);
    pk.h[2] = __float2bfloat16(v.z*scale*gv.z);
    pk.h[3] = __float2bfloat16(v.w*scale*gv.w);
    ((ushort4*)(x + (size_t)row * DMODEL))[tid] = pk.u;
}

// ---------------- transpose + convert: W[K,N] f32 -> Wt[N,K] bf16 ----------
__global__ __launch_bounds__(256) void transpose_bf16(const float* __restrict__ W,
                                                      __hip_bfloat16* __restrict__ Wt,
                                                      int K, int N) {
    __shared__ float t[32][33];
    int n0 = blockIdx.x * 32, k0 = blockIdx.y * 32;
    int c = threadIdx.x & 31, r = threadIdx.x >> 5;   // 8 rows per pass
    #pragma unroll
    for (int rr = 0; rr < 32; rr += 8)
        t[rr + r][c] = W[(size_t)(k0 + rr + r)*N + n0 + c];
    __syncthreads();
    #pragma unroll
    for (int rr = 0; rr < 32; rr += 8)
        Wt[(size_t)(n0 + rr + r)*K + k0 + c] = __float2bfloat16(t[c][rr + r]);
}

// ---------------- bf16 MFMA GEMM: C[M,N] = A[M,K] @ Bt[N,K]^T, C f32 -------
// 128x128 tile, BK=32, 256 threads = 4 waves (2x2), 64x64 per wave.
__device__ __forceinline__ void gld16(const __hip_bfloat16* g, __hip_bfloat16* l) {
    __builtin_amdgcn_global_load_lds((const __attribute__((address_space(1))) void*)g,
                                     (__attribute__((address_space(3))) void*)l, 16, 0, 0);
}

__global__ __launch_bounds__(256, 2) void gemm_bf16(const __hip_bfloat16* __restrict__ A,
                                                    const __hip_bfloat16* __restrict__ Bt,
                                                    float* __restrict__ C,
                                                    int M, int N, int K) {
    __shared__ __hip_bfloat16 As[128*32];
    __shared__ __hip_bfloat16 Bs[128*32];
    const int tid = threadIdx.x;
    const int wid = tid >> 6, lane = tid & 63;
    const int bm = blockIdx.y * 128, bn = blockIdx.x * 128;
    const int wm = (wid >> 1) * 64, wn = (wid & 1) * 64;

    f32x4 acc[4][4];
    #pragma unroll
    for (int i = 0; i < 4; ++i)
        #pragma unroll
        for (int j = 0; j < 4; ++j)
            acc[i][j] = (f32x4){0.f, 0.f, 0.f, 0.f};

    // staging: tile = 512 chunks of 16B; chunk c -> row c>>2, col8grp c&3
    const int c0 = wid*64 + lane;
    const int c1 = 256 + c0;
    const int r0 = c0 >> 2, kg0 = (c0 & 3) << 3;
    const int r1 = c1 >> 2, kg1 = (c1 & 3) << 3;
    const __hip_bfloat16* A0 = A + (size_t)(bm + r0)*K + kg0;
    const __hip_bfloat16* A1 = A + (size_t)(bm + r1)*K + kg1;
    const __hip_bfloat16* B0 = Bt + (size_t)(bn + r0)*K + kg0;
    const __hip_bfloat16* B1 = Bt + (size_t)(bn + r1)*K + kg1;

    const int fr = lane & 15;                // fragment row/col
    const int fk = (lane >> 4) << 3;         // fragment k offset

    for (int k0 = 0; k0 < K; k0 += 32) {
        gld16(A0 + k0, As + wid*512);
        gld16(A1 + k0, As + 2048 + wid*512);
        gld16(B0 + k0, Bs + wid*512);
        gld16(B1 + k0, Bs + 2048 + wid*512);
        __syncthreads();

        short8v a[4], b[4];
        #pragma unroll
        for (int mt = 0; mt < 4; ++mt)
            a[mt] = *(const short8v*)&As[(wm + mt*16 + fr)*32 + fk];
        #pragma unroll
        for (int nt = 0; nt < 4; ++nt)
            b[nt] = *(const short8v*)&Bs[(wn + nt*16 + fr)*32 + fk];
        #pragma unroll
        for (int mt = 0; mt < 4; ++mt)
            #pragma unroll
            for (int nt = 0; nt < 4; ++nt)
                acc[mt][nt] = __builtin_amdgcn_mfma_f32_16x16x32_bf16(a[mt], b[nt], acc[mt][nt], 0, 0, 0);
        __syncthreads();
    }

    // C/D layout: col = lane&15, row = (lane>>4)*4 + reg
    const int rsub = (lane >> 4) << 2;
    #pragma unroll
    for (int mt = 0; mt < 4; ++mt) {
        int rbase = bm + wm + mt*16 + rsub;
        #pragma unroll
        for (int nt = 0; nt < 4; ++nt) {
            int col = bn + wn + nt*16 + fr;
            #pragma unroll
            for (int r = 0; r < 4; ++r)
                C[(size_t)(rbase + r)*N + col] = acc[mt][nt][r];
        }
    }
}

// ---------------- RoPE (interleaved pairs) on q,k sections of qkv ----------
__global__ __launch_bounds__(256) void rope_kernel(float* __restrict__ qkv) {
    int idx = blockIdx.x*256 + threadIdx.x;
    int row = idx >> 9;
    int c4  = (idx & 511) << 2;
    int n   = row & (NTOK - 1);
    int d   = c4 & (DH - 1);
    int p0  = d >> 1;
    float e0 = (float)p0 * (1.f/32.f);
    float inv0 = powf(10000.f, -e0);
    float inv1 = powf(10000.f, -(e0 + 1.f/32.f));
    float a0 = (float)n * inv0;
    float a1 = (float)n * inv1;
    float s0, c0, s1, c1;
    sincosf(a0, &s0, &c0);
    sincosf(a1, &s1, &c1);
    float* ptr = qkv + (size_t)row*QKVC + c4;
    float4 v = *(float4*)ptr;
    float4 o;
    o.x = v.x*c0 - v.y*s0;
    o.y = v.y*c0 + v.x*s0;
    o.z = v.z*c1 - v.w*s1;
    o.w = v.w*c1 + v.z*s1;
    *(float4*)ptr = o;
}

// ---------------- windowed causal attention, f32, bf16 output --------------
__global__ __launch_bounds__(256) void attn_kernel(const float* __restrict__ qkv,
                                                   const float* __restrict__ pm,
                                                   __hip_bfloat16* __restrict__ ao) {
    const int rb = blockIdx.x;
    const int h  = blockIdx.y;
    const int s  = blockIdx.z;
    const int b_idx = s >> 3, w_idx = s & 7;
    const int tid = threadIdx.x;
    const int i = rb*256 + tid;
    const size_t base_row = (size_t)b_idx*NTOK + (size_t)w_idx*SEG_;

    __shared__ float kb[64][68];
    __shared__ float vb[64][68];

    float q[DH];
    {
        const float* qrow = qkv + (base_row + i)*QKVC + h*DH;
        #pragma unroll
        for (int d = 0; d < DH; d += 4) {
            float4 t = *(const float4*)(qrow + d);
            q[d]=t.x; q[d+1]=t.y; q[d+2]=t.z; q[d+3]=t.w;
        }
    }
    float m = -3.0e38f, l = 0.0f;
    float acc[DH];
    #pragma unroll
    for (int d = 0; d < DH; ++d) acc[d] = 0.f;

    {
        int j = tid >> 4, c = (tid & 15) << 2;
        *(float4*)&kb[j][c] = *(const float4*)&pm[((size_t)(0*HEADS_ + h)*PMEM + j)*DH + c];
        *(float4*)&vb[j][c] = *(const float4*)&pm[((size_t)(1*HEADS_ + h)*PMEM + j)*DH + c];
    }
    __syncthreads();
    #pragma unroll 1
    for (int j = 0; j < PMEM; ++j) {
        float sc = 0.f;
        #pragma unroll
        for (int d = 0; d < DH; ++d) sc += q[d]*kb[j][d];
        sc *= 0.125f;
        if (sc > m) {
            float corr = __expf(m - sc);
            l *= corr;
            #pragma unroll
            for (int d = 0; d < DH; ++d) acc[d] *= corr;
            m = sc;
        }
        float p = __expf(sc - m);
        l += p;
        #pragma unroll
        for (int d = 0; d < DH; ++d) acc[d] += p*vb[j][d];
    }

    for (int c0 = 0; c0 < (rb+1)*256; c0 += 64) {
        __syncthreads();
        #pragma unroll
        for (int lld = 0; lld < 4; ++lld) {
            int lin = lld*256 + tid;
            int j = lin >> 4, c = (lin & 15) << 2;
            size_t grow = (base_row + c0 + j)*QKVC + h*DH;
            *(float4*)&kb[j][c] = *(const float4*)&qkv[grow + 1024 + c];
            *(float4*)&vb[j][c] = *(const float4*)&qkv[grow + 2048 + c];
        }
        __syncthreads();
        int jmax = min(64, i - c0 + 1);
        #pragma unroll 1
        for (int j = 0; j < jmax; ++j) {
            float sc = 0.f;
            #pragma unroll
            for (int d = 0; d < DH; ++d) sc += q[d]*kb[j][d];
            sc *= 0.125f;
            if (sc > m) {
                float corr = __expf(m - sc);
                l *= corr;
                #pragma unroll
                for (int d = 0; d < DH; ++d) acc[d] *= corr;
                m = sc;
            }
            float p = __expf(sc - m);
            l += p;
            #pragma unroll
            for (int d = 0; d < DH; ++d) acc[d] += p*vb[j][d];
        }
    }

    float inv = 1.0f / l;
    __hip_bfloat16* orow = ao + (base_row + i)*DMODEL + h*DH;
    #pragma unroll
    for (int d = 0; d < DH; d += 4) {
        union { ushort4 u; __hip_bfloat16 h[4]; } pk;
        pk.h[0] = __float2bfloat16(acc[d+0]*inv);
        pk.h[1] = __float2bfloat16(acc[d+1]*inv);
        pk.h[2] = __float2bfloat16(acc[d+2]*inv);
        pk.h[3] = __float2bfloat16(acc[d+3]*inv);
        *(ushort4*)&orow[d] = pk.u;
    }
}

extern "C" void kernel_launch(void* const* d_in, const int* in_sizes, int n_in,
                              void* d_out, int out_size, void* d_ws, size_t ws_size,
                              hipStream_t stream) {
    const float* seq  = (const float*)d_in[0];
    const float* g    = (const float*)d_in[1];
    const float* wqkv = (const float*)d_in[2];
    const float* wout = (const float*)d_in[3];
    const float* pm   = (const float*)d_in[4];
    float* out = (float*)d_out;

    char* ws = (char*)d_ws;
    float* qkv            = (float*)ws;                                   // 96 MB
    __hip_bfloat16* xb    = (__hip_bfloat16*)(ws + 100663296);            // 16 MB (x, later ao)
    __hip_bfloat16* wqkvt = (__hip_bfloat16*)(ws + 100663296 + 16777216); // 6 MB
    __hip_bfloat16* woutt = (__hip_bfloat16*)(ws + 100663296 + 16777216 + 6291456); // 2 MB

    transpose_bf16<<<dim3(QKVC/32, DMODEL/32), 256, 0, stream>>>(wqkv, wqkvt, DMODEL, QKVC);
    transpose_bf16<<<dim3(DMODEL/32, DMODEL/32), 256, 0, stream>>>(wout, woutt, DMODEL, DMODEL);
    rmsnorm_bf16<<<ROWS, 256, 0, stream>>>(seq, g, xb);
    gemm_bf16<<<dim3(QKVC/128, ROWS/128), 256, 0, stream>>>(xb, wqkvt, qkv, ROWS, QKVC, DMODEL);
    rope_kernel<<<(ROWS*2048/4)/256, 256, 0, stream>>>(qkv);
    attn_kernel<<<dim3(2, 16, 16), 256, 0, stream>>>(qkv, pm, xb);
    gemm_bf16<<<dim3(DMODEL/128, ROWS/128), 256, 0, stream>>>(xb, woutt, out, ROWS, DMODEL, DMODEL);
}

// Round 3
// 280.203 us; speedup vs baseline: 4.3078x; 1.8681x over previous
//
#include <hip/hip_runtime.h>
#include <hip/hip_bf16.h>

typedef __attribute__((ext_vector_type(8))) short short8v;
typedef __attribute__((ext_vector_type(4))) float f32x4;

#define B_ 2
#define NTOK 4096
#define DMODEL 1024
#define HEADS_ 16
#define DH 64
#define SEG_ 512
#define PMEM 16
#define ROWS 8192      // B_*NTOK
#define QKVC 3072

// ---------------- RMSNorm -> bf16 ----------------
__global__ __launch_bounds__(256) void rmsnorm_bf16(const float* __restrict__ seq,
                                                    const float* __restrict__ g,
                                                    __hip_bfloat16* __restrict__ x) {
    int row = blockIdx.x;
    const float4* in = (const float4*)(seq + (size_t)row * DMODEL);
    int tid = threadIdx.x;
    float4 v = in[tid];
    float ss = v.x*v.x + v.y*v.y + v.z*v.z + v.w*v.w;
    #pragma unroll
    for (int off = 32; off >= 1; off >>= 1) ss += __shfl_xor(ss, off, 64);
    __shared__ float red[4];
    if ((tid & 63) == 0) red[tid >> 6] = ss;
    __syncthreads();
    float tot = red[0] + red[1] + red[2] + red[3];
    float scale = rsqrtf(tot * (1.0f/(float)DMODEL) + 1.1920929e-7f);
    float4 gv = ((const float4*)g)[tid];
    union { ushort4 u; __hip_bfloat16 h[4]; } pk;
    pk.h[0] = __float2bfloat16(v.x*scale*gv.x);
    pk.h[1] = __float2bfloat16(v.y*scale*gv.y);
    pk.h[2] = __float2bfloat16(v.z*scale*gv.z);
    pk.h[3] = __float2bfloat16(v.w*scale*gv.w);
    ((ushort4*)(x + (size_t)row * DMODEL))[tid] = pk.u;
}

// ---------------- transpose + convert: W[K,N] f32 -> Wt[N,K] bf16 ----------
__global__ __launch_bounds__(256) void transpose_bf16(const float* __restrict__ W,
                                                      __hip_bfloat16* __restrict__ Wt,
                                                      int K, int N) {
    __shared__ float t[32][33];
    int n0 = blockIdx.x * 32, k0 = blockIdx.y * 32;
    int c = threadIdx.x & 31, r = threadIdx.x >> 5;
    #pragma unroll
    for (int rr = 0; rr < 32; rr += 8)
        t[rr + r][c] = W[(size_t)(k0 + rr + r)*N + n0 + c];
    __syncthreads();
    #pragma unroll
    for (int rr = 0; rr < 32; rr += 8)
        Wt[(size_t)(n0 + rr + r)*K + k0 + c] = __float2bfloat16(t[c][rr + r]);
}

// ---------------- bf16 MFMA GEMM: C[M,N] = A[M,K] @ Bt[N,K]^T, C f32 -------
__device__ __forceinline__ void gld16(const __hip_bfloat16* g, __hip_bfloat16* l) {
    __builtin_amdgcn_global_load_lds((const __attribute__((address_space(1))) void*)g,
                                     (__attribute__((address_space(3))) void*)l, 16, 0, 0);
}

__global__ __launch_bounds__(256, 2) void gemm_bf16(const __hip_bfloat16* __restrict__ A,
                                                    const __hip_bfloat16* __restrict__ Bt,
                                                    float* __restrict__ C,
                                                    int M, int N, int K) {
    __shared__ __hip_bfloat16 As[128*32];
    __shared__ __hip_bfloat16 Bs[128*32];
    const int tid = threadIdx.x;
    const int wid = tid >> 6, lane = tid & 63;
    const int bm = blockIdx.y * 128, bn = blockIdx.x * 128;
    const int wm = (wid >> 1) * 64, wn = (wid & 1) * 64;

    f32x4 acc[4][4];
    #pragma unroll
    for (int i = 0; i < 4; ++i)
        #pragma unroll
        for (int j = 0; j < 4; ++j)
            acc[i][j] = (f32x4){0.f, 0.f, 0.f, 0.f};

    const int c0 = wid*64 + lane;
    const int c1 = 256 + c0;
    const int r0 = c0 >> 2, kg0 = (c0 & 3) << 3;
    const int r1 = c1 >> 2, kg1 = (c1 & 3) << 3;
    const __hip_bfloat16* A0 = A + (size_t)(bm + r0)*K + kg0;
    const __hip_bfloat16* A1 = A + (size_t)(bm + r1)*K + kg1;
    const __hip_bfloat16* B0 = Bt + (size_t)(bn + r0)*K + kg0;
    const __hip_bfloat16* B1 = Bt + (size_t)(bn + r1)*K + kg1;

    const int fr = lane & 15;
    const int fk = (lane >> 4) << 3;

    for (int k0 = 0; k0 < K; k0 += 32) {
        gld16(A0 + k0, As + wid*512);
        gld16(A1 + k0, As + 2048 + wid*512);
        gld16(B0 + k0, Bs + wid*512);
        gld16(B1 + k0, Bs + 2048 + wid*512);
        __syncthreads();

        short8v a[4], b[4];
        #pragma unroll
        for (int mt = 0; mt < 4; ++mt)
            a[mt] = *(const short8v*)&As[(wm + mt*16 + fr)*32 + fk];
        #pragma unroll
        for (int nt = 0; nt < 4; ++nt)
            b[nt] = *(const short8v*)&Bs[(wn + nt*16 + fr)*32 + fk];
        #pragma unroll
        for (int mt = 0; mt < 4; ++mt)
            #pragma unroll
            for (int nt = 0; nt < 4; ++nt)
                acc[mt][nt] = __builtin_amdgcn_mfma_f32_16x16x32_bf16(a[mt], b[nt], acc[mt][nt], 0, 0, 0);
        __syncthreads();
    }

    const int rsub = (lane >> 4) << 2;
    #pragma unroll
    for (int mt = 0; mt < 4; ++mt) {
        int rbase = bm + wm + mt*16 + rsub;
        #pragma unroll
        for (int nt = 0; nt < 4; ++nt) {
            int col = bn + wn + nt*16 + fr;
            #pragma unroll
            for (int r = 0; r < 4; ++r)
                C[(size_t)(rbase + r)*N + col] = acc[mt][nt][r];
        }
    }
}

// ---------------- RoPE (interleaved pairs) on q,k sections of qkv ----------
__global__ __launch_bounds__(256) void rope_kernel(float* __restrict__ qkv) {
    int idx = blockIdx.x*256 + threadIdx.x;
    int row = idx >> 9;
    int c4  = (idx & 511) << 2;
    int n   = row & (NTOK - 1);
    int d   = c4 & (DH - 1);
    int p0  = d >> 1;
    float e0 = (float)p0 * (1.f/32.f);
    float inv0 = powf(10000.f, -e0);
    float inv1 = powf(10000.f, -(e0 + 1.f/32.f));
    float a0 = (float)n * inv0;
    float a1 = (float)n * inv1;
    float s0, c0, s1, c1;
    sincosf(a0, &s0, &c0);
    sincosf(a1, &s1, &c1);
    float* ptr = qkv + (size_t)row*QKVC + c4;
    float4 v = *(float4*)ptr;
    float4 o;
    o.x = v.x*c0 - v.y*s0;
    o.y = v.y*c0 + v.x*s0;
    o.z = v.z*c1 - v.w*s1;
    o.w = v.w*c1 + v.z*s1;
    *(float4*)ptr = o;
}

// ---------------- MFMA flash attention ------------------------------------
// grid (16 seg, 16 head), 512 threads = 8 waves; wave w owns q-rows
// {mt*128 + w*16 + 0..15 : mt=0..3}. KV tiles of 64 keys (tile0 = 16 pmem +
// 48 seg keys), double-buffered LDS. K as [key][d], V transposed [d][key],
// P per-wave [qrow][key]; all rows XOR-swizzled: byte ^= (row&7)<<4.
__device__ __forceinline__ void stage_load(const float* __restrict__ qkv,
                                           const float* __restrict__ pm,
                                           int h, int srow, int tt, int skey, int sdg,
                                           float4 kv[4]) {
    int kg = tt*64 + skey;
    if (kg < PMEM) {
        const float* kp = pm + ((size_t)h*PMEM + kg)*DH + sdg;
        const float* vp = pm + ((size_t)(HEADS_ + h)*PMEM + kg)*DH + sdg;
        kv[0] = *(const float4*)kp;      kv[1] = *(const float4*)(kp + 4);
        kv[2] = *(const float4*)vp;      kv[3] = *(const float4*)(vp + 4);
    } else {
        int r = min(kg - PMEM, SEG_ - 1);   // clamp tail (masked anyway)
        const float* bp = qkv + (size_t)(srow + r)*QKVC + h*DH + sdg;
        kv[0] = *(const float4*)(bp + 1024); kv[1] = *(const float4*)(bp + 1028);
        kv[2] = *(const float4*)(bp + 2048); kv[3] = *(const float4*)(bp + 2052);
    }
}

__device__ __forceinline__ void stage_write(__hip_bfloat16* Kb, __hip_bfloat16* Vb,
                                            int skey, int sdg, const float4 kv[4]) {
    union { uint4 u; __hip_bfloat16 hh[8]; } pk;
    const float kf[8] = {kv[0].x,kv[0].y,kv[0].z,kv[0].w, kv[1].x,kv[1].y,kv[1].z,kv[1].w};
    #pragma unroll
    for (int j = 0; j < 8; ++j) pk.hh[j] = __float2bfloat16(kf[j]);
    *(uint4*)((char*)Kb + ((skey*128 + sdg*2) ^ ((skey&7)<<4))) = pk.u;
    const float vf[8] = {kv[2].x,kv[2].y,kv[2].z,kv[2].w, kv[3].x,kv[3].y,kv[3].z,kv[3].w};
    #pragma unroll
    for (int j = 0; j < 8; ++j) {
        int d = sdg + j;
        *(__hip_bfloat16*)((char*)Vb + ((d*128 + skey*2) ^ ((d&7)<<4))) = __float2bfloat16(vf[j]);
    }
}

__global__ __launch_bounds__(512, 2) void attn_mfma(const float* __restrict__ qkv,
                                                    const float* __restrict__ pm,
                                                    __hip_bfloat16* __restrict__ ao) {
    __shared__ __hip_bfloat16 KB[2][4096];
    __shared__ __hip_bfloat16 VB[2][4096];
    __shared__ __hip_bfloat16 PB[8][4096];

    const int s = blockIdx.x, h = blockIdx.y;
    const int srow = (s >> 3)*NTOK + (s & 7)*SEG_;
    const int tid = threadIdx.x;
    const int w = tid >> 6, lane = tid & 63;
    const int g = lane >> 4, fr = lane & 15;
    const int rsub = g * 4;
    char* Pw = (char*)&PB[w][0];

    // Q fragments (scaled by dh^-0.5), resident for the whole kernel
    short8v aq[4][2];
    #pragma unroll
    for (int mt = 0; mt < 4; ++mt) {
        const float* qp = qkv + (size_t)(srow + mt*128 + w*16 + fr)*QKVC + h*DH;
        #pragma unroll
        for (int ks = 0; ks < 2; ++ks) {
            float4 q0 = *(const float4*)(qp + ks*32 + g*8);
            float4 q1 = *(const float4*)(qp + ks*32 + g*8 + 4);
            union { short8v v; __hip_bfloat16 hh[8]; } u;
            u.hh[0] = __float2bfloat16(q0.x*0.125f); u.hh[1] = __float2bfloat16(q0.y*0.125f);
            u.hh[2] = __float2bfloat16(q0.z*0.125f); u.hh[3] = __float2bfloat16(q0.w*0.125f);
            u.hh[4] = __float2bfloat16(q1.x*0.125f); u.hh[5] = __float2bfloat16(q1.y*0.125f);
            u.hh[6] = __float2bfloat16(q1.z*0.125f); u.hh[7] = __float2bfloat16(q1.w*0.125f);
            aq[mt][ks] = u.v;
        }
    }

    f32x4 accO[4][4];
    float m_[4][4], l_[4][4];
    #pragma unroll
    for (int mt = 0; mt < 4; ++mt) {
        #pragma unroll
        for (int dt = 0; dt < 4; ++dt) accO[mt][dt] = (f32x4){0.f,0.f,0.f,0.f};
        #pragma unroll
        for (int r = 0; r < 4; ++r) { m_[mt][r] = -1e30f; l_[mt][r] = 0.f; }
    }

    const int skey = tid >> 3, sdg = (tid & 7) * 8;

    {   // prologue: stage tile 0
        float4 kv[4];
        stage_load(qkv, pm, h, srow, 0, skey, sdg, kv);
        stage_write(&KB[0][0], &VB[0][0], skey, sdg, kv);
    }
    __syncthreads();

    for (int t = 0; t <= 8; ++t) {
        const int bf = t & 1;
        float4 kvn[4];
        if (t < 8) stage_load(qkv, pm, h, srow, t + 1, skey, sdg, kvn);

        char* Kb = (char*)&KB[bf][0];
        char* Vb = (char*)&VB[bf][0];

        short8v bk[4][2];
        #pragma unroll
        for (int nt = 0; nt < 4; ++nt)
            #pragma unroll
            for (int ks = 0; ks < 2; ++ks) {
                int row = nt*16 + fr;
                bk[nt][ks] = *(const short8v*)(Kb + ((row*128 + ks*64 + g*16) ^ ((row&7)<<4)));
            }

        #pragma unroll
        for (int mt = 0; mt < 4; ++mt) {
            const int qb = mt*128 + w*16;
            if (t > 0 && t*64 > qb + 31) continue;       // fully masked tile

            f32x4 sA[4];
            #pragma unroll
            for (int nt = 0; nt < 4; ++nt) sA[nt] = (f32x4){0.f,0.f,0.f,0.f};
            #pragma unroll
            for (int ks = 0; ks < 2; ++ks)
                #pragma unroll
                for (int nt = 0; nt < 4; ++nt)
                    sA[nt] = __builtin_amdgcn_mfma_f32_16x16x32_bf16(aq[mt][ks], bk[nt][ks], sA[nt], 0, 0, 0);

            if (!(t*64 + 63 <= qb + 16)) {               // need masking
                #pragma unroll
                for (int nt = 0; nt < 4; ++nt) {
                    int kg2 = t*64 + nt*16 + fr;
                    #pragma unroll
                    for (int r = 0; r < 4; ++r) {
                        int irow = qb + rsub + r;
                        if (!((kg2 < PMEM) || (kg2 <= irow + PMEM))) sA[nt][r] = -1e30f;
                    }
                }
            }

            float mx[4], corr[4], rs[4];
            #pragma unroll
            for (int r = 0; r < 4; ++r)
                mx[r] = fmaxf(fmaxf(sA[0][r], sA[1][r]), fmaxf(sA[2][r], sA[3][r]));
            #pragma unroll
            for (int r = 0; r < 4; ++r) {
                #pragma unroll
                for (int off = 1; off <= 8; off <<= 1)
                    mx[r] = fmaxf(mx[r], __shfl_xor(mx[r], off, 64));
                float mn = fmaxf(m_[mt][r], mx[r]);
                corr[r] = __expf(m_[mt][r] - mn);
                m_[mt][r] = mn;
            }
            #pragma unroll
            for (int nt = 0; nt < 4; ++nt)
                #pragma unroll
                for (int r = 0; r < 4; ++r)
                    sA[nt][r] = __expf(sA[nt][r] - m_[mt][r]);
            #pragma unroll
            for (int r = 0; r < 4; ++r) {
                rs[r] = sA[0][r] + sA[1][r] + sA[2][r] + sA[3][r];
                #pragma unroll
                for (int off = 1; off <= 8; off <<= 1)
                    rs[r] += __shfl_xor(rs[r], off, 64);
                l_[mt][r] = l_[mt][r]*corr[r] + rs[r];
            }
            #pragma unroll
            for (int dt = 0; dt < 4; ++dt)
                #pragma unroll
                for (int r = 0; r < 4; ++r)
                    accO[mt][dt][r] *= corr[r];

            // P -> per-wave LDS (bf16)
            #pragma unroll
            for (int nt = 0; nt < 4; ++nt)
                #pragma unroll
                for (int r = 0; r < 4; ++r) {
                    int row_l = mt*16 + rsub + r;
                    *(__hip_bfloat16*)(Pw + ((row_l*128 + (nt*16 + fr)*2) ^ ((row_l&7)<<4))) =
                        __float2bfloat16(sA[nt][r]);
                }

            // O += P @ V
            #pragma unroll
            for (int ks2 = 0; ks2 < 2; ++ks2) {
                int arow = mt*16 + fr;
                short8v ap = *(const short8v*)(Pw + ((arow*128 + ks2*64 + g*16) ^ ((arow&7)<<4)));
                #pragma unroll
                for (int dt = 0; dt < 4; ++dt) {
                    int vrow = dt*16 + fr;
                    short8v bv = *(const short8v*)(Vb + ((vrow*128 + ks2*64 + g*16) ^ ((vrow&7)<<4)));
                    accO[mt][dt] = __builtin_amdgcn_mfma_f32_16x16x32_bf16(ap, bv, accO[mt][dt], 0, 0, 0);
                }
            }
        }

        if (t < 8) stage_write(&KB[bf^1][0], &VB[bf^1][0], skey, sdg, kvn);
        __syncthreads();
    }

    // epilogue: O/l -> per-wave LDS -> coalesced bf16 stores
    #pragma unroll
    for (int mt = 0; mt < 4; ++mt) {
        float inv[4];
        #pragma unroll
        for (int r = 0; r < 4; ++r) inv[r] = 1.0f / l_[mt][r];
        #pragma unroll
        for (int dt = 0; dt < 4; ++dt)
            #pragma unroll
            for (int r = 0; r < 4; ++r) {
                int row_l = mt*16 + rsub + r;
                *(__hip_bfloat16*)(Pw + ((row_l*128 + (dt*16 + fr)*2) ^ ((row_l&7)<<4))) =
                    __float2bfloat16(accO[mt][dt][r] * inv[r]);
            }
    }
    #pragma unroll
    for (int c = 0; c < 8; ++c) {
        int row_l = c*8 + (lane >> 3);
        int mt = row_l >> 4, rloc = row_l & 15;
        size_t grow = (size_t)(srow + mt*128 + w*16 + rloc);
        uint4 v = *(const uint4*)(Pw + ((row_l*128 + (lane&7)*16) ^ ((row_l&7)<<4)));
        *(uint4*)((char*)(ao + grow*DMODEL + h*DH) + (lane&7)*16) = v;
    }
}

extern "C" void kernel_launch(void* const* d_in, const int* in_sizes, int n_in,
                              void* d_out, int out_size, void* d_ws, size_t ws_size,
                              hipStream_t stream) {
    const float* seq  = (const float*)d_in[0];
    const float* g    = (const float*)d_in[1];
    const float* wqkv = (const float*)d_in[2];
    const float* wout = (const float*)d_in[3];
    const float* pm   = (const float*)d_in[4];
    float* out = (float*)d_out;

    char* ws = (char*)d_ws;
    float* qkv            = (float*)ws;                                   // 96 MB
    __hip_bfloat16* xb    = (__hip_bfloat16*)(ws + 100663296);            // 16 MB (x, later ao)
    __hip_bfloat16* wqkvt = (__hip_bfloat16*)(ws + 100663296 + 16777216); // 6 MB
    __hip_bfloat16* woutt = (__hip_bfloat16*)(ws + 100663296 + 16777216 + 6291456); // 2 MB

    transpose_bf16<<<dim3(QKVC/32, DMODEL/32), 256, 0, stream>>>(wqkv, wqkvt, DMODEL, QKVC);
    transpose_bf16<<<dim3(DMODEL/32, DMODEL/32), 256, 0, stream>>>(wout, woutt, DMODEL, DMODEL);
    rmsnorm_bf16<<<ROWS, 256, 0, stream>>>(seq, g, xb);
    gemm_bf16<<<dim3(QKVC/128, ROWS/128), 256, 0, stream>>>(xb, wqkvt, qkv, ROWS, QKVC, DMODEL);
    rope_kernel<<<(ROWS*2048/4)/256, 256, 0, stream>>>(qkv);
    attn_mfma<<<dim3(16, 16), 512, 0, stream>>>(qkv, pm, xb);
    gemm_bf16<<<dim3(DMODEL/128, ROWS/128), 256, 0, stream>>>(xb, woutt, out, ROWS, DMODEL, DMODEL);
}